// Round 14
// baseline (195.586 us; speedup 1.0000x reference)
//
#include <hip/hip_runtime.h>

// HyperMixer fused kernel, MI355X (gfx950).
// x[B=2,S=4096,K=4,D=2048] f32, out[B,S,D] f32, W[24][8192] f32,
// scale[3], base[24]. Output = concat(y[B,S,K,D], collapsed[B,S,D]) f32.
//
// Round-14: TOKS=4 + __launch_bounds__(512, 2).
// r13 finding: compiler clamped VGPR to 52 (same as r12), re-serializing
// the hand-written load pipeline -> null result. Empirical launch-bounds
// calibration (r7: arg2=8 -> cap 32, r8: arg2=4 -> cap 64) gives
// arg2=2 -> cap 128: enough for the real live set (~106: 12 accs +
// 2-stage x/W uint4 pipeline + 4 prefetched out float4). TOKS=4 halves
// W L2 traffic vs TOKS=3 (2048 blocks x 384 KB = 0.79 GB) and doubles
// dot2-per-W-load. Occupancy drops to ~2 blocks/CU -- r12 proved
// occupancy is not the limiter (42->61% occ, zero time change).
// Validated & kept: f16 x in LDS, f16 W (conv pre-pass, L2-resident),
// v_dot2_f32_f16, scalar in-register sinkhorn (4 lanes), bounded unroll.
// Spill check: WRITE_SIZE must stay exactly 327,680 KB.

#define EPS 1e-6f
constexpr int K_ = 4, D_ = 2048, KD = 8192, NOUT = 24;
constexpr int NTOK = 2 * 4096;          // 8192 tokens
constexpr int TPB = 512;
constexpr int TOKS = 4;
constexpr int NBLK = NTOK / TOKS;       // 2048

typedef _Float16 h2 __attribute__((ext_vector_type(2)));

static __device__ __forceinline__ unsigned int pk2(float a, float b) {
    h2 h; h.x = (_Float16)a; h.y = (_Float16)b;
    return __builtin_bit_cast(unsigned int, h);
}

static __device__ __forceinline__ float dot2(unsigned int w, unsigned int x, float c) {
#if __has_builtin(__builtin_amdgcn_fdot2)
    return __builtin_amdgcn_fdot2(__builtin_bit_cast(h2, w),
                                  __builtin_bit_cast(h2, x), c, false);
#else
    h2 hw = __builtin_bit_cast(h2, w), hx = __builtin_bit_cast(h2, x);
    return c + (float)hw.x * (float)hx.x + (float)hw.y * (float)hx.y;
#endif
}

static __device__ __forceinline__ float frcp(float v) {
#if __has_builtin(__builtin_amdgcn_rcpf)
    return __builtin_amdgcn_rcpf(v);
#else
    return 1.f / v;
#endif
}

// Wh: linear f16 of W. Thread g converts 8 consecutive floats.
__global__ void conv_w_kernel(const float* __restrict__ W, unsigned int* __restrict__ Wh) {
    int g = blockIdx.x * blockDim.x + threadIdx.x;   // 24576 threads
    const float* src = W + (size_t)g * 8;
    float4 a = *reinterpret_cast<const float4*>(src);
    float4 b = *reinterpret_cast<const float4*>(src + 4);
    uint4 u;
    u.x = pk2(a.x, a.y); u.y = pk2(a.z, a.w);
    u.z = pk2(b.x, b.y); u.w = pk2(b.z, b.w);
    *reinterpret_cast<uint4*>(Wh + (size_t)g * 4) = u;
}

__global__ __launch_bounds__(TPB, 2) void hypermix_kernel(
    const float* __restrict__ x, const float* __restrict__ outp,
    const unsigned int* __restrict__ Wh,
    const float* __restrict__ scale, const float* __restrict__ base,
    float* __restrict__ y, float* __restrict__ coll)
{
    const int t = threadIdx.x;
    const int w = t >> 6, lane = t & 63;
    const size_t gt0 = (size_t)blockIdx.x * TOKS;

    __shared__ unsigned int xh[TOKS][KD / 2];  // packed f16 x, 64 KB
    __shared__ float ssred[TOKS][8];           // per-wave sumsq partials
    __shared__ float lg[TOKS][24];             // raw dot products
    __shared__ float wts[TOKS][24];            // 0..3 pre, 4..7 post, 8..23 comb

    // ---- phase 0: stage 4 tokens (pipelined), prefetch out into regs ----
    float4 ovr[4];
#pragma unroll 2
    for (int tt = 0; tt < TOKS; ++tt) {
        const float* xb = x + (gt0 + tt) * KD + t * 4;
        float4 v[4];
#pragma unroll
        for (int i = 0; i < 4; ++i)
            v[i] = *reinterpret_cast<const float4*>(xb + i * 2048);
        ovr[tt] = *reinterpret_cast<const float4*>(outp + (gt0 + tt) * D_ + t * 4);
        float ss = 0.f;
#pragma unroll
        for (int i = 0; i < 4; ++i) {
            ss += v[i].x * v[i].x + v[i].y * v[i].y + v[i].z * v[i].z + v[i].w * v[i].w;
            uint2 p; p.x = pk2(v[i].x, v[i].y); p.y = pk2(v[i].z, v[i].w);
            *reinterpret_cast<uint2*>(&xh[tt][i * 1024 + t * 2]) = p;
        }
#pragma unroll
        for (int m = 1; m < 64; m <<= 1) ss += __shfl_xor(ss, m, 64);
        if (lane == 0) ssred[tt][w] = ss;
    }
    __syncthreads();

    // ---- phase A: wave w -> rows 3w..3w+2, 4 tokens, 2-stage pipeline ----
    {
        const int r0 = w * 3;
        const unsigned int* Wp0 = Wh + (size_t)(r0 + 0) * 4096;
        const unsigned int* Wp1 = Wh + (size_t)(r0 + 1) * 4096;
        const unsigned int* Wp2 = Wh + (size_t)(r0 + 2) * 4096;
        float acc[3][4];
#pragma unroll
        for (int j = 0; j < 3; ++j)
#pragma unroll
            for (int tt = 0; tt < 4; ++tt) acc[j][tt] = 0.f;

        uint4 xa0, xa1, xa2, xa3, wa0, wa1, wa2;
        uint4 xb0, xb1, xb2, xb3, wb0, wb1, wb2;

#define LOADIT(X0, X1, X2, X3, W0, W1, W2, IT) do {                          \
        const int gi4 = ((IT) * 64 + lane) * 4;                              \
        X0 = *reinterpret_cast<const uint4*>(&xh[0][gi4]);                   \
        X1 = *reinterpret_cast<const uint4*>(&xh[1][gi4]);                   \
        X2 = *reinterpret_cast<const uint4*>(&xh[2][gi4]);                   \
        X3 = *reinterpret_cast<const uint4*>(&xh[3][gi4]);                   \
        W0 = *reinterpret_cast<const uint4*>(Wp0 + gi4);                     \
        W1 = *reinterpret_cast<const uint4*>(Wp1 + gi4);                     \
        W2 = *reinterpret_cast<const uint4*>(Wp2 + gi4);                     \
    } while (0)
#define DOT4(A, WV, XV) do {                                                 \
        A = dot2(WV.x, XV.x, A); A = dot2(WV.y, XV.y, A);                    \
        A = dot2(WV.z, XV.z, A); A = dot2(WV.w, XV.w, A);                    \
    } while (0)
#define CONSUME(X0, X1, X2, X3, W0, W1, W2) do {                             \
        DOT4(acc[0][0], W0, X0); DOT4(acc[0][1], W0, X1);                    \
        DOT4(acc[0][2], W0, X2); DOT4(acc[0][3], W0, X3);                    \
        DOT4(acc[1][0], W1, X0); DOT4(acc[1][1], W1, X1);                    \
        DOT4(acc[1][2], W1, X2); DOT4(acc[1][3], W1, X3);                    \
        DOT4(acc[2][0], W2, X0); DOT4(acc[2][1], W2, X1);                    \
        DOT4(acc[2][2], W2, X2); DOT4(acc[2][3], W2, X3);                    \
    } while (0)

        LOADIT(xa0, xa1, xa2, xa3, wa0, wa1, wa2, 0);
#pragma unroll 1
        for (int it2 = 0; it2 < 7; ++it2) {
            LOADIT(xb0, xb1, xb2, xb3, wb0, wb1, wb2, 2 * it2 + 1);
            CONSUME(xa0, xa1, xa2, xa3, wa0, wa1, wa2);
            LOADIT(xa0, xa1, xa2, xa3, wa0, wa1, wa2, 2 * it2 + 2);
            CONSUME(xb0, xb1, xb2, xb3, wb0, wb1, wb2);
        }
        LOADIT(xb0, xb1, xb2, xb3, wb0, wb1, wb2, 15);
        CONSUME(xa0, xa1, xa2, xa3, wa0, wa1, wa2);
        CONSUME(xb0, xb1, xb2, xb3, wb0, wb1, wb2);
#undef LOADIT
#undef DOT4
#undef CONSUME

#pragma unroll
        for (int j = 0; j < 3; ++j)
#pragma unroll
            for (int tt = 0; tt < 4; ++tt) {
                float v = acc[j][tt];
#pragma unroll
                for (int m = 1; m < 64; m <<= 1) v += __shfl_xor(v, m, 64);
                if (lane == 0) lg[tt][r0 + j] = v;
            }
    }
    __syncthreads();

    // ---- weights: scalar per-token (4 lanes), sinkhorn fully in regs ----
    if (t < TOKS) {
        float ss = ssred[t][0] + ssred[t][1] + ssred[t][2] + ssred[t][3]
                 + ssred[t][4] + ssred[t][5] + ssred[t][6] + ssred[t][7];
        float rms = rsqrtf(ss * (1.f / 8192.f) + EPS);
        float s0 = scale[0], s1 = scale[1], s2 = scale[2];
        float l[24];
#pragma unroll
        for (int i = 0; i < 24; ++i) l[i] = lg[t][i];
#pragma unroll
        for (int k = 0; k < 4; ++k) {
            float z0 = l[k] * rms * s0 + base[k];
            wts[t][k] = frcp(1.f + __expf(-z0)) + EPS;
            float z1 = l[4 + k] * rms * s1 + base[4 + k];
            wts[t][4 + k] = 2.f * frcp(1.f + __expf(-z1));
        }
        float p[16];
#pragma unroll
        for (int h = 0; h < 4; ++h) {
            float c0 = l[8 + h * 4 + 0] * rms * s2 + base[8 + h * 4 + 0];
            float c1 = l[8 + h * 4 + 1] * rms * s2 + base[8 + h * 4 + 1];
            float c2 = l[8 + h * 4 + 2] * rms * s2 + base[8 + h * 4 + 2];
            float c3 = l[8 + h * 4 + 3] * rms * s2 + base[8 + h * 4 + 3];
            float mx = fmaxf(fmaxf(c0, c1), fmaxf(c2, c3));
            float e0 = __expf(c0 - mx), e1 = __expf(c1 - mx);
            float e2 = __expf(c2 - mx), e3 = __expf(c3 - mx);
            float inv = frcp(e0 + e1 + e2 + e3);
            p[h * 4 + 0] = e0 * inv + EPS; p[h * 4 + 1] = e1 * inv + EPS;
            p[h * 4 + 2] = e2 * inv + EPS; p[h * 4 + 3] = e3 * inv + EPS;
        }
#pragma unroll
        for (int k = 0; k < 4; ++k) {
            float inv = frcp(p[k] + p[4 + k] + p[8 + k] + p[12 + k] + EPS);
            p[k] *= inv; p[4 + k] *= inv; p[8 + k] *= inv; p[12 + k] *= inv;
        }
#pragma unroll 1
        for (int itn = 0; itn < 19; ++itn) {
#pragma unroll
            for (int h = 0; h < 4; ++h) {
                float inv = frcp(p[h * 4] + p[h * 4 + 1] + p[h * 4 + 2] + p[h * 4 + 3] + EPS);
                p[h * 4] *= inv; p[h * 4 + 1] *= inv; p[h * 4 + 2] *= inv; p[h * 4 + 3] *= inv;
            }
#pragma unroll
            for (int k = 0; k < 4; ++k) {
                float inv = frcp(p[k] + p[4 + k] + p[8 + k] + p[12 + k] + EPS);
                p[k] *= inv; p[4 + k] *= inv; p[8 + k] *= inv; p[12 + k] *= inv;
            }
        }
#pragma unroll
        for (int i = 0; i < 16; ++i) wts[t][8 + i] = p[i];
    }
    __syncthreads();

    // ---- phase B: per token, all 512 threads, out already in regs ----
#pragma unroll 1
    for (int tt = 0; tt < TOKS; ++tt) {
        float pre[4], post[4], cmb[4][4];
#pragma unroll
        for (int k = 0; k < 4; ++k) { pre[k] = wts[tt][k]; post[k] = wts[tt][4 + k]; }
#pragma unroll
        for (int h = 0; h < 4; ++h)
#pragma unroll
            for (int k = 0; k < 4; ++k) cmb[h][k] = wts[tt][8 + h * 4 + k];

        const int d = t * 4;
        float xk[4][4];
#pragma unroll
        for (int k = 0; k < 4; ++k) {
            uint2 pq = *reinterpret_cast<const uint2*>(&xh[tt][k * 1024 + t * 2]);
            h2 h0 = __builtin_bit_cast(h2, pq.x), h1 = __builtin_bit_cast(h2, pq.y);
            xk[k][0] = (float)h0.x; xk[k][1] = (float)h0.y;
            xk[k][2] = (float)h1.x; xk[k][3] = (float)h1.y;
        }
        float* yb = y + (gt0 + tt) * KD;
        float* cb = coll + (gt0 + tt) * D_;
        float cv[4], yv[4];
#pragma unroll
        for (int e = 0; e < 4; ++e)
            cv[e] = pre[0] * xk[0][e] + pre[1] * xk[1][e]
                  + pre[2] * xk[2][e] + pre[3] * xk[3][e];
        *reinterpret_cast<float4*>(cb + d) = make_float4(cv[0], cv[1], cv[2], cv[3]);
        const float oe[4] = {ovr[tt].x, ovr[tt].y, ovr[tt].z, ovr[tt].w};
#pragma unroll
        for (int h = 0; h < 4; ++h) {
#pragma unroll
            for (int e = 0; e < 4; ++e)
                yv[e] = post[h] * oe[e] + cmb[h][0] * xk[0][e] + cmb[h][1] * xk[1][e]
                      + cmb[h][2] * xk[2][e] + cmb[h][3] * xk[3][e];
            *reinterpret_cast<float4*>(yb + h * D_ + d) =
                make_float4(yv[0], yv[1], yv[2], yv[3]);
        }
    }
}

extern "C" void kernel_launch(void* const* d_in, const int* in_sizes, int n_in,
                              void* d_out, int out_size, void* d_ws, size_t ws_size,
                              hipStream_t stream) {
    const float* x     = (const float*)d_in[0];
    const float* outp  = (const float*)d_in[1];
    const float* W     = (const float*)d_in[2];
    const float* scale = (const float*)d_in[3];
    const float* base  = (const float*)d_in[4];
    float* y    = (float*)d_out;
    float* coll = y + (size_t)NTOK * KD;   // 67108864

    unsigned int* Wh = (unsigned int*)d_ws;     // 384 KB f16 (ws is larger)
    conv_w_kernel<<<NOUT * KD / 8 / 256, 256, 0, stream>>>(W, Wh);
    hypermix_kernel<<<NBLK, TPB, 0, stream>>>(x, outp, Wh, scale, base, y, coll);
}